// Round 3
// baseline (63.037 us; speedup 1.0000x reference)
//
#include <hip/hip_runtime.h>

#define NV    6890
#define NB    64
#define NCOL  192            // NB * 3 output columns per row
#define CAP_W 256            // per-wave LDS nonzero-CHUNK capacity
#define MAIN4 1722           // aligned float4 count per row ( (NV-2)/4 )
#define NIT   14             // ceil(MAIN4 / 128) double-wide iterations
#define SCALE (1.0f / (64.0f * 6890.0f))

// ---------------------------------------------------------------------------
// Kernel 1: transpose x[b][w][d] -> Xt[w][b*3+d] so per-nonzero gathers are
// coalesced 256B reads.
// ---------------------------------------------------------------------------
__global__ __launch_bounds__(256) void transpose_x_kernel(
    const float* __restrict__ x, float* __restrict__ Xt) {
  int i = blockIdx.x * blockDim.x + threadIdx.x;
  const int total = NB * NV * 3;
  if (i >= total) return;
  int d = i % 3;
  int w = (i / 3) % NV;
  int b = i / (3 * NV);
  Xt[(size_t)w * NCOL + b * 3 + d] = x[i];
}

// ---------------------------------------------------------------------------
// Kernel 2: ONE WAVE per Laplacian row; zero barriers.
//  Scan: 2x float4 per lane per iter (2KiB/wave-iter). Compaction at CHUNK
//        granularity: one ballot + one ds_write_b128 per nonzero float4.
//  Apply: unpack chunks from LDS (broadcast); zero values skipped behind a
//        wave-uniform branch; 3 coalesced gathers per true nonzero.
// ---------------------------------------------------------------------------
template <bool USE_XT, bool USE_PARTIALS>
__global__ __launch_bounds__(256) void lap_rows_wave_kernel(
    const float* __restrict__ L,
    const float* __restrict__ X,          // Xt if USE_XT, else raw x
    float* __restrict__ partials,
    float* __restrict__ out_atomic) {
  const int lane = threadIdx.x & 63;
  const int wv   = threadIdx.x >> 6;
  const int v    = blockIdx.x * 4 + wv;
  if (v >= NV) return;                    // whole-wave exit; no barriers used

  __shared__ float4 s_c4[4][CAP_W];
  __shared__ int    s_cb[4][CAP_W];
  float4* __restrict__ sc4 = s_c4[wv];
  int*    __restrict__ scb = s_cb[wv];

  const float* __restrict__ row = L + (size_t)v * NV;
  const int head     = (v & 1) ? 2 : 0;            // odd rows: 8B-misaligned start
  const int extraPos = head ? 0 : (NV - 2);        // the 2 floats outside the f4 body
  const float4* __restrict__ m4 = (const float4*)(row + head);

  const unsigned long long lmask = (1ull << lane) - 1ull;

  // Column ownership: lane handles columns {lane, lane+64, lane+128}.
  const int n0 = lane, n1 = lane + 64, n2 = lane + 128;
  // Fallback (non-transposed) per-lane gather offsets: col n -> b=n/3, d=n%3.
  const size_t o0 = (size_t)(n0 / 3) * (NV * 3) + (n0 % 3);
  const size_t o1 = (size_t)(n1 / 3) * (NV * 3) + (n1 % 3);
  const size_t o2 = (size_t)(n2 / 3) * (NV * 3) + (n2 % 3);

  float a0 = 0.f, a1 = 0.f, a2 = 0.f;
  int nnz = 0;                                     // wave-uniform chunk count

  auto gather3 = [&](float val, int col) {
    if (USE_XT) {
      const float* __restrict__ xr = X + (size_t)col * NCOL;
      a0 = fmaf(val, xr[n0], a0);
      a1 = fmaf(val, xr[n1], a1);
      a2 = fmaf(val, xr[n2], a2);
    } else {
      const size_t cb = (size_t)col * 3;
      a0 = fmaf(val, X[cb + o0], a0);
      a1 = fmaf(val, X[cb + o1], a1);
      a2 = fmaf(val, X[cb + o2], a2);
    }
  };

  auto apply = [&](int count) {
    for (int j = 0; j < count; ++j) {              // uniform j: LDS broadcast
      float4 f = sc4[j];
      int    cb = scb[j];
      if (f.x != 0.f) gather3(f.x, cb);            // uniform branches: execz-skip
      if (f.y != 0.f) gather3(f.y, cb + 1);
      if (f.z != 0.f) gather3(f.z, cb + 2);
      if (f.w != 0.f) gather3(f.w, cb + 3);
    }
  };

  auto push_chunk = [&](bool nz, float4 f, int colbase) {
    unsigned long long m = __ballot(nz);
    if (nz) {
      int pos = nnz + __popcll(m & lmask);
      sc4[pos] = f;
      scb[pos] = colbase;
    }
    nnz += __popcll(m);                            // uniform
  };

  // 2-float head (odd rows) / tail (even rows): push as (val,0,0,0) chunks.
  {
    const bool act = lane < 2;
    const int  col = extraPos + lane;
    float val = act ? row[col] : 0.f;
    push_chunk(val != 0.f, make_float4(val, 0.f, 0.f, 0.f), col);
  }

  // Aligned float4 body: NIT double-wide wave-uniform iterations, no barriers.
  for (int it = 0; it < NIT; ++it) {
    const int i0 = it * 128 + lane;
    const int i1 = i0 + 64;
    float4 f0 = make_float4(0.f, 0.f, 0.f, 0.f);
    float4 f1 = make_float4(0.f, 0.f, 0.f, 0.f);
    if (i0 < MAIN4) f0 = m4[i0];
    if (i1 < MAIN4) f1 = m4[i1];
    const bool nz0 = (f0.x != 0.f) | (f0.y != 0.f) | (f0.z != 0.f) | (f0.w != 0.f);
    const bool nz1 = (f1.x != 0.f) | (f1.y != 0.f) | (f1.z != 0.f) | (f1.w != 0.f);
    push_chunk(nz0, f0, head + i0 * 4);
    push_chunk(nz1, f1, head + i1 * 4);
    if (nnz > CAP_W - 130) { apply(nnz); nnz = 0; }   // pathological-row guard
  }
  apply(nnz);

  // Row contribution: sum acc^2 over this wave's 3 columns, then wave-reduce.
  float sq = fmaf(a0, a0, fmaf(a1, a1, a2 * a2));
  #pragma unroll
  for (int o = 32; o > 0; o >>= 1) sq += __shfl_down(sq, o);
  if (lane == 0) {
    if (USE_PARTIALS) partials[v] = sq;
    else              atomicAdd(out_atomic, sq * SCALE);
  }
}

// ---------------------------------------------------------------------------
// Kernel 3: deterministic fixed-order reduction of the 6890 row partials.
// ---------------------------------------------------------------------------
__global__ __launch_bounds__(256) void reduce_kernel(
    const float* __restrict__ p, float* __restrict__ out) {
  int tid = threadIdx.x;
  float a = 0.0f;
  for (int i = tid; i < NV; i += 256) a += p[i];
  #pragma unroll
  for (int o = 32; o > 0; o >>= 1) a += __shfl_down(a, o);
  __shared__ float s_w[4];
  if ((tid & 63) == 0) s_w[tid >> 6] = a;
  __syncthreads();
  if (tid == 0) out[0] = (s_w[0] + s_w[1] + s_w[2] + s_w[3]) * SCALE;
}

__global__ void zero_out_kernel(float* p) {
  if (threadIdx.x == 0 && blockIdx.x == 0) p[0] = 0.0f;
}

// ---------------------------------------------------------------------------
extern "C" void kernel_launch(void* const* d_in, const int* in_sizes, int n_in,
                              void* d_out, int out_size, void* d_ws, size_t ws_size,
                              hipStream_t stream) {
  const float* x = (const float*)d_in[0];   // [64, 6890, 3] f32
  const float* L = (const float*)d_in[1];   // [6890, 6890] f32
  float* out = (float*)d_out;               // scalar f32

  const size_t xt_bytes   = (size_t)NV * NCOL * sizeof(float);  // ~5.3 MB
  const size_t part_bytes = (size_t)NV * sizeof(float);         // ~27.5 KB
  const int grid = (NV + 3) / 4;

  if (ws_size >= xt_bytes + part_bytes) {
    float* Xt       = (float*)d_ws;
    float* partials = (float*)((char*)d_ws + xt_bytes);
    const int total = NB * NV * 3;
    transpose_x_kernel<<<(total + 255) / 256, 256, 0, stream>>>(x, Xt);
    lap_rows_wave_kernel<true, true><<<grid, 256, 0, stream>>>(L, Xt, partials, nullptr);
    reduce_kernel<<<1, 256, 0, stream>>>(partials, out);
  } else if (ws_size >= part_bytes) {
    float* partials = (float*)d_ws;
    lap_rows_wave_kernel<false, true><<<grid, 256, 0, stream>>>(L, x, partials, nullptr);
    reduce_kernel<<<1, 256, 0, stream>>>(partials, out);
  } else {
    zero_out_kernel<<<1, 64, 0, stream>>>(out);
    lap_rows_wave_kernel<false, false><<<grid, 256, 0, stream>>>(L, x, nullptr, out);
  }
}

// Round 4
// 58.048 us; speedup vs baseline: 1.0859x; 1.0859x over previous
//
#include <hip/hip_runtime.h>

#define NV    6890
#define NB    64
#define NCOL  192            // NB * 3 output columns per row
#define MAIN4 1722           // aligned float4 count per row ( (NV-2)/4 )
#define NIT   14             // ceil(MAIN4 / 128) double-wide iterations
#define SCALE (1.0f / (64.0f * 6890.0f))

// ---------------------------------------------------------------------------
// Kernel 1: transpose x[b][w][d] -> Xt[w][b*3+d]. Thread i = w*192 + n so
// WRITES are perfectly coalesced; reads are 4B gathers that L2 absorbs
// (consecutive blocks touch consecutive w -> high line reuse).
// ---------------------------------------------------------------------------
__global__ __launch_bounds__(256) void transpose_x_kernel(
    const float* __restrict__ x, float* __restrict__ Xt) {
  int i = blockIdx.x * blockDim.x + threadIdx.x;
  const int total = NV * NCOL;
  if (i >= total) return;
  int n = i % NCOL;
  int w = i / NCOL;
  int b = n / 3;
  int d = n % 3;
  Xt[i] = x[(size_t)b * (NV * 3) + (size_t)w * 3 + d];
}

// ---------------------------------------------------------------------------
// Kernel 2: ONE WAVE per Laplacian row. No LDS, no barriers, no capacity
// limits. Scan reads 2x float4/lane/iter with branch-free next-iter prefetch.
// Nonzeros are consumed straight off the ballot mask: uniform ctz bit-loop,
// v_readlane broadcast, 3 coalesced 256B gathers from Xt + 3 FMAs each.
// Deterministic order (fixed bit order within fixed iteration order).
// ---------------------------------------------------------------------------
template <bool USE_XT, bool USE_PARTIALS>
__global__ __launch_bounds__(256) void lap_rows_wave_kernel(
    const float* __restrict__ L,
    const float* __restrict__ X,          // Xt if USE_XT, else raw x
    float* __restrict__ partials,
    float* __restrict__ out_atomic) {
  const int lane = threadIdx.x & 63;
  const int wv   = threadIdx.x >> 6;
  const int v    = blockIdx.x * 4 + wv;
  if (v >= NV) return;                    // whole-wave exit

  const float* __restrict__ row = L + (size_t)v * NV;
  const int head     = (v & 1) ? 2 : 0;          // odd rows: 8B-misaligned start
  const int extraPos = head ? 0 : (NV - 2);      // 2 floats outside the f4 body
  const float4* __restrict__ m4 = (const float4*)(row + head);

  // Column ownership: lane handles columns {lane, lane+64, lane+128}.
  const int n0 = lane, n1 = lane + 64, n2 = lane + 128;
  // Fallback (non-transposed) per-lane gather offsets: col n -> b=n/3, d=n%3.
  const size_t o0 = (size_t)(n0 / 3) * (NV * 3) + (n0 % 3);
  const size_t o1 = (size_t)(n1 / 3) * (NV * 3) + (n1 % 3);
  const size_t o2 = (size_t)(n2 / 3) * (NV * 3) + (n2 % 3);

  float a0 = 0.f, a1 = 0.f, a2 = 0.f;

  // Walk set bits of a (wave-uniform) ballot mask; broadcast val via readlane.
  auto proc = [&](unsigned long long m, float src, int col0, int stride) {
    while (m) {
      const int s = (int)__builtin_ctzll(m);
      m &= m - 1;
      const float val =
          __int_as_float(__builtin_amdgcn_readlane(__float_as_int(src), s));
      const int col = col0 + s * stride;
      if (USE_XT) {
        const float* __restrict__ xr = X + (size_t)col * NCOL;
        a0 = fmaf(val, xr[n0], a0);
        a1 = fmaf(val, xr[n1], a1);
        a2 = fmaf(val, xr[n2], a2);
      } else {
        const size_t cb = (size_t)col * 3;
        a0 = fmaf(val, X[cb + o0], a0);
        a1 = fmaf(val, X[cb + o1], a1);
        a2 = fmaf(val, X[cb + o2], a2);
      }
    }
  };

  // 2-float head (odd rows) / tail (even rows).
  {
    const bool act = lane < 2;
    const float val = act ? row[extraPos + lane] : 0.f;
    proc(__ballot(act && val != 0.f), val, extraPos, 1);
  }

  // Pipelined 2x-float4 body: prefetch next iteration with clamped indices
  // (branch-free; last prefetch degenerates to a broadcast of m4[MAIN4-1]).
  float4 c0 = m4[lane];                    // lane < 64 << MAIN4: always valid
  float4 c1 = m4[lane + 64];
  for (int it = 0; it < NIT; ++it) {
    const int i0 = it * 128 + lane;
    const int i1 = i0 + 64;
    const int j0 = min(i0 + 128, MAIN4 - 1);
    const int j1 = min(i1 + 128, MAIN4 - 1);
    const float4 p0 = m4[j0];              // next-iter prefetch (always legal)
    const float4 p1 = m4[j1];

    const bool act0 = i0 < MAIN4;
    const bool act1 = i1 < MAIN4;
    const unsigned long long mx0 = __ballot(act0 && c0.x != 0.f);
    const unsigned long long my0 = __ballot(act0 && c0.y != 0.f);
    const unsigned long long mz0 = __ballot(act0 && c0.z != 0.f);
    const unsigned long long mw0 = __ballot(act0 && c0.w != 0.f);
    const unsigned long long mx1 = __ballot(act1 && c1.x != 0.f);
    const unsigned long long my1 = __ballot(act1 && c1.y != 0.f);
    const unsigned long long mz1 = __ballot(act1 && c1.z != 0.f);
    const unsigned long long mw1 = __ballot(act1 && c1.w != 0.f);

    const int base0 = head + it * 512;     // col of chunk (it*128 + s) slot x
    const int base1 = base0 + 256;
    proc(mx0, c0.x, base0 + 0, 4);
    proc(my0, c0.y, base0 + 1, 4);
    proc(mz0, c0.z, base0 + 2, 4);
    proc(mw0, c0.w, base0 + 3, 4);
    proc(mx1, c1.x, base1 + 0, 4);
    proc(my1, c1.y, base1 + 1, 4);
    proc(mz1, c1.z, base1 + 2, 4);
    proc(mw1, c1.w, base1 + 3, 4);

    c0 = p0;
    c1 = p1;
  }

  // Row contribution: sum acc^2 over this wave's 3 columns, then wave-reduce.
  float sq = fmaf(a0, a0, fmaf(a1, a1, a2 * a2));
  #pragma unroll
  for (int o = 32; o > 0; o >>= 1) sq += __shfl_down(sq, o);
  if (lane == 0) {
    if (USE_PARTIALS) partials[v] = sq;
    else              atomicAdd(out_atomic, sq * SCALE);
  }
}

// ---------------------------------------------------------------------------
// Kernel 3: deterministic fixed-order reduction of the 6890 row partials.
// ---------------------------------------------------------------------------
__global__ __launch_bounds__(256) void reduce_kernel(
    const float* __restrict__ p, float* __restrict__ out) {
  int tid = threadIdx.x;
  float a = 0.0f;
  for (int i = tid; i < NV; i += 256) a += p[i];
  #pragma unroll
  for (int o = 32; o > 0; o >>= 1) a += __shfl_down(a, o);
  __shared__ float s_w[4];
  if ((tid & 63) == 0) s_w[tid >> 6] = a;
  __syncthreads();
  if (tid == 0) out[0] = (s_w[0] + s_w[1] + s_w[2] + s_w[3]) * SCALE;
}

__global__ void zero_out_kernel(float* p) {
  if (threadIdx.x == 0 && blockIdx.x == 0) p[0] = 0.0f;
}

// ---------------------------------------------------------------------------
extern "C" void kernel_launch(void* const* d_in, const int* in_sizes, int n_in,
                              void* d_out, int out_size, void* d_ws, size_t ws_size,
                              hipStream_t stream) {
  const float* x = (const float*)d_in[0];   // [64, 6890, 3] f32
  const float* L = (const float*)d_in[1];   // [6890, 6890] f32
  float* out = (float*)d_out;               // scalar f32

  const size_t xt_bytes   = (size_t)NV * NCOL * sizeof(float);  // ~5.3 MB
  const size_t part_bytes = (size_t)NV * sizeof(float);         // ~27.5 KB
  const int grid = (NV + 3) / 4;

  if (ws_size >= xt_bytes + part_bytes) {
    float* Xt       = (float*)d_ws;
    float* partials = (float*)((char*)d_ws + xt_bytes);
    const int total = NV * NCOL;
    transpose_x_kernel<<<(total + 255) / 256, 256, 0, stream>>>(x, Xt);
    lap_rows_wave_kernel<true, true><<<grid, 256, 0, stream>>>(L, Xt, partials, nullptr);
    reduce_kernel<<<1, 256, 0, stream>>>(partials, out);
  } else if (ws_size >= part_bytes) {
    float* partials = (float*)d_ws;
    lap_rows_wave_kernel<false, true><<<grid, 256, 0, stream>>>(L, x, partials, nullptr);
    reduce_kernel<<<1, 256, 0, stream>>>(partials, out);
  } else {
    zero_out_kernel<<<1, 64, 0, stream>>>(out);
    lap_rows_wave_kernel<false, false><<<grid, 256, 0, stream>>>(L, x, nullptr, out);
  }
}